// Round 1
// baseline (544.749 us; speedup 1.0000x reference)
//
#include <hip/hip_runtime.h>
#include <math.h>

// LCGLoss: B=256, L=512, D=512.
// S[(b,l),k] = (text @ C^T)[(b,l),k],  C[k][d] = bf16( (ip @ W_ML)[k][d] / tau )
// loss = mean over valid (i,l) of 0.5*(denom_log + logaddexp(s_iji, cross_log[i])) - s_iji
//
// GEMM is barrier-free / LDS-free: 2 waves/block, each wave owns 32 rows x 256 cols.
// A (f32) streams HBM->reg->cvt; B streams L2->reg in fragment layout from a
// chunk-major Cb2 [kq=64][col=256][8] written by c_kernel. Counted vmcnt pipeline,
// no __syncthreads in the main loop. LDS only used by the fused epilogue.

#define B_ 256
#define L_ 512
#define D_ 512
#define ROWS (B_ * L_)      // 131072
#define NT (ROWS / 64)      // 2048 row-tiles
#define NEG_INF (-INFINITY)

typedef __attribute__((ext_vector_type(8))) short s8_t;     // 8 bf16 in 4 VGPRs
typedef __attribute__((ext_vector_type(4))) float f4_t;
typedef __attribute__((ext_vector_type(2))) float f2_t;
typedef __attribute__((ext_vector_type(4))) unsigned short us4_t;

__device__ inline unsigned short f2bf(float x) {
    unsigned int u = __float_as_uint(x);
    u += 0x7FFFu + ((u >> 16) & 1u);          // round-to-nearest-even
    return (unsigned short)(u >> 16);
}

// ---------------- K0: ip[k][e] = sum_d img[k][d]*Wmv[e][d]; 32k x 64e tiles, 64 blocks ----
__global__ __launch_bounds__(256) void ip_kernel(const float* __restrict__ img,
                                                 const float* __restrict__ Wmv,
                                                 float* __restrict__ ip) {
    int kt = blockIdx.x >> 3, et = blockIdx.x & 7;
    __shared__ float Ast[32][36];   // [d][krow]  (transposed)
    __shared__ float Bst[32][72];   // [d][ecol]  (transposed, 16B-aligned rows)
    int tid = threadIdx.x;
    int ty = tid >> 4;              // 0..15 -> rows ty*2
    int tx = tid & 15;              // cols tx*4
    float acc[2][4] = {};
    int sr = tid >> 3, sc = (tid & 7) * 4;
    for (int d0 = 0; d0 < D_; d0 += 32) {
        f4_t a = *(const f4_t*)(img + (size_t)(kt * 32 + sr) * D_ + d0 + sc);
        f4_t b0 = *(const f4_t*)(Wmv + (size_t)(et * 64 + sr) * D_ + d0 + sc);
        f4_t b1 = *(const f4_t*)(Wmv + (size_t)(et * 64 + sr + 32) * D_ + d0 + sc);
        __syncthreads();
#pragma unroll
        for (int m = 0; m < 4; m++) {
            Ast[sc + m][sr] = a[m];
            Bst[sc + m][sr] = b0[m];
            Bst[sc + m][sr + 32] = b1[m];
        }
        __syncthreads();
#pragma unroll 4
        for (int d = 0; d < 32; d++) {
            f2_t a2 = *(const f2_t*)&Ast[d][ty * 2];
            f4_t b4 = *(const f4_t*)&Bst[d][tx * 4];
#pragma unroll
            for (int i = 0; i < 2; i++)
#pragma unroll
                for (int j = 0; j < 4; j++) acc[i][j] = fmaf(a2[i], b4[j], acc[i][j]);
        }
    }
#pragma unroll
    for (int i = 0; i < 2; i++) {
        f4_t o; o[0] = acc[i][0]; o[1] = acc[i][1]; o[2] = acc[i][2]; o[3] = acc[i][3];
        *(f4_t*)(ip + (size_t)(kt * 32 + ty * 2 + i) * D_ + et * 64 + tx * 4) = o;
    }
}

// ---------------- K1: Cb2[kq][n][j] = bf16( sum_e ip[n][e]*Wml[e][kk] / tau ) -------------
// Chunk-major layout: element (n, kk) at Cb2[(kk>>3)*256*8 + n*8 + (kk&7)].
__global__ __launch_bounds__(256) void c_kernel(const float* __restrict__ ip,
                                                const float* __restrict__ Wml,
                                                const float* __restrict__ tau,
                                                unsigned short* __restrict__ Cb2) {
    int kt = blockIdx.x >> 3, dt = blockIdx.x & 7;
    __shared__ float Ast[32][36];   // [e][krow] (transposed)
    __shared__ float Bst[32][72];   // [e][dcol] (direct rows of Wml)
    int tid = threadIdx.x;
    int ty = tid >> 4;
    int tx = tid & 15;
    float acc[2][4] = {};
    int sr = tid >> 3, sc = (tid & 7) * 4;       // A staging
    int br = tid >> 4, bc = (tid & 15) * 4;      // B staging (16 rows x 64 cols per pass)
    for (int e0 = 0; e0 < D_; e0 += 32) {
        f4_t a = *(const f4_t*)(ip + (size_t)(kt * 32 + sr) * D_ + e0 + sc);
        f4_t b0 = *(const f4_t*)(Wml + (size_t)(e0 + br) * D_ + dt * 64 + bc);
        f4_t b1 = *(const f4_t*)(Wml + (size_t)(e0 + br + 16) * D_ + dt * 64 + bc);
        __syncthreads();
#pragma unroll
        for (int m = 0; m < 4; m++) Ast[sc + m][sr] = a[m];
        *(f4_t*)&Bst[br][bc] = b0;
        *(f4_t*)&Bst[br + 16][bc] = b1;
        __syncthreads();
#pragma unroll 4
        for (int e = 0; e < 32; e++) {
            f2_t a2 = *(const f2_t*)&Ast[e][ty * 2];
            f4_t b4 = *(const f4_t*)&Bst[e][tx * 4];
#pragma unroll
            for (int i = 0; i < 2; i++)
#pragma unroll
                for (int j = 0; j < 4; j++) acc[i][j] = fmaf(a2[i], b4[j], acc[i][j]);
        }
    }
    float it = 1.0f / fmaxf(tau[0], 0.001f);
#pragma unroll
    for (int i = 0; i < 2; i++) {
        us4_t o;
#pragma unroll
        for (int j = 0; j < 4; j++) o[j] = f2bf(acc[i][j] * it);
        int n = kt * 32 + ty * 2 + i;           // output col (image index)
        int kk0 = dt * 64 + tx * 4;             // GEMM-K coordinate of o[0]
        *(us4_t*)(Cb2 + (size_t)((kk0 >> 3) * 256 + n) * 8 + (kk0 & 7)) = o;
    }
}

// ---------------- Kmask: mbits[l*4+w] bit j = valid[w*64+j, l] ----------------
__global__ __launch_bounds__(256) void mask_kernel(const int* __restrict__ pad,
                                                   unsigned long long* __restrict__ mbits) {
    int l = blockIdx.x;
    int w = threadIdx.x >> 6;
    int j = threadIdx.x & 63;
    unsigned long long bal = __ballot(pad[(w * 64 + j) * L_ + l] == 0);
    if (j == 0) mbits[l * 4 + w] = bal;
}

// ---------------- K2: barrier-free bf16 MFMA GEMM (64x256 per block, 2 waves) ------------
__global__ __launch_bounds__(128, 2) void gemm_mfma_kernel(
    const float* __restrict__ text, const unsigned short* __restrict__ Cb2,
    const unsigned long long* __restrict__ mbits,
    float* __restrict__ denom, float* __restrict__ siji,
    float* __restrict__ crossM, float* __restrict__ crossS) {
    // LDS used only by the epilogue: Sh[32][257] + pm/ps[128] + rvadj[32]
    __shared__ __align__(16) float lds[8512];
    float* Sh    = lds;
    float* pm    = lds + 8224;
    float* ps    = lds + 8352;
    float* rvadj = lds + 8480;

    const int tile = blockIdx.x;
    const int row0 = tile * 64;
    const int bIdx = row0 >> 9;
    const int l0 = row0 & 511;
    const int tid = threadIdx.x;
    const int wave = tid >> 6;
    const int lane = tid & 63;
    const int qd = lane >> 4;       // k-quad within chunk
    const int mm = lane & 15;       // row (A) / col (B) within 16-tile

    f4_t acc[2][16];
#pragma unroll
    for (int mt = 0; mt < 2; mt++)
#pragma unroll
        for (int nt = 0; nt < 16; nt++)
#pragma unroll
            for (int r = 0; r < 4; r++) acc[mt][nt][r] = 0.f;

    // A: wave-private 32 rows; fragment mt covers rows wrow + mt*16 + mm, k = qd*8+j.
    const int wrow = row0 + wave * 32;
    const float* aB0 = text + (size_t)(wrow + mm) * D_ + qd * 8;
    const float* aB1 = aB0 + 16 * D_;
    // B: chunk t, frag nt at Cb2[(t*4+qd)*2048 + (nt*16+mm)*8] (shorts).
    const unsigned short* bB = Cb2 + qd * 2048 + mm * 8;

    f4_t ar[4];                 // raw f32 A for chunk t (loaded one chunk ahead)
    s8_t aa[2];                 // converted bf16 A fragments
    s8_t bcur[8], bnxt[8];      // B fragment halves (nt 0..7 / 8..15)

#define LOAD_A(t) do { \
        ar[0] = *(const f4_t*)(aB0 + (t) * 32); \
        ar[1] = *(const f4_t*)(aB0 + (t) * 32 + 4); \
        ar[2] = *(const f4_t*)(aB1 + (t) * 32); \
        ar[3] = *(const f4_t*)(aB1 + (t) * 32 + 4); \
    } while (0)
#define LOAD_BH(dst, t, half) do { \
        _Pragma("unroll") \
        for (int nt = 0; nt < 8; nt++) \
            dst[nt] = *(const s8_t*)(bB + (t) * 8192 + (half) * 1024 + nt * 128); \
    } while (0)

    LOAD_A(0);
    LOAD_BH(bcur, 0, 0);
#pragma unroll 1
    for (int t = 0; t < 16; t++) {
        LOAD_BH(bnxt, t, 1);                       // issue half1(t)
#pragma unroll
        for (int q = 0; q < 2; q++) {              // cvt A(t) -> bf16 frags
            s8_t a8;
#pragma unroll
            for (int j = 0; j < 4; j++) {
                a8[j]     = (short)f2bf(ar[2 * q][j]);
                a8[j + 4] = (short)f2bf(ar[2 * q + 1][j]);
            }
            aa[q] = a8;
        }
        int tn = (t + 1) & 15;                     // wrap keeps loads in-bounds; t=15
        LOAD_A(tn);                                //   prefetches are dead (DCE-able)
#pragma unroll
        for (int nt = 0; nt < 8; nt++) {           // MFMA half0 (bcur resident)
            acc[0][nt] = __builtin_amdgcn_mfma_f32_16x16x32_bf16(aa[0], bcur[nt], acc[0][nt], 0, 0, 0);
            acc[1][nt] = __builtin_amdgcn_mfma_f32_16x16x32_bf16(aa[1], bcur[nt], acc[1][nt], 0, 0, 0);
        }
        LOAD_BH(bcur, tn, 0);                      // issue half0(t+1) into freed regs
#pragma unroll
        for (int nt = 0; nt < 8; nt++) {           // MFMA half1 (bnxt ~200cy old)
            acc[0][8 + nt] = __builtin_amdgcn_mfma_f32_16x16x32_bf16(aa[0], bnxt[nt], acc[0][8 + nt], 0, 0, 0);
            acc[1][8 + nt] = __builtin_amdgcn_mfma_f32_16x16x32_bf16(aa[1], bnxt[nt], acc[1][8 + nt], 0, 0, 0);
        }
    }
#undef LOAD_A
#undef LOAD_BH

    // -------- epilogue: two 32-row halves through LDS; branch-free masked reductions -----
    // acc[mt][nt][r] -> row (in wave) = mt*16 + qd*4 + r, col = nt*16 + mm.
    // 128 threads: each handles cross cols tid and tid+128.
    float cm0 = NEG_INF, cs0 = 0.f, cm1 = NEG_INF, cs1 = 0.f;
    const int mw = bIdx >> 6, mb = bIdx & 63;

#pragma unroll
    for (int h = 0; h < 2; h++) {
        __syncthreads();
        if (wave == h) {
#pragma unroll
            for (int mt = 0; mt < 2; mt++)
#pragma unroll
                for (int nt = 0; nt < 16; nt++)
#pragma unroll
                    for (int r = 0; r < 4; r++)
                        Sh[(mt * 16 + qd * 4 + r) * 257 + nt * 16 + mm] = acc[mt][nt][r];
        }
        if (tid < 32) {
            int l = l0 + h * 32 + tid;
            rvadj[tid] = ((mbits[l * 4 + mw] >> mb) & 1ULL) ? 0.f : NEG_INF;
        }
        __syncthreads();

        // cross partials for columns tid and tid+128 (exclusion of col==bIdx at the end)
        {
            float m2 = NEG_INF, m3 = NEG_INF;
#pragma unroll 8
            for (int r = 0; r < 32; r++) {
                float adj = rvadj[r];
                m2 = fmaxf(m2, Sh[r * 257 + tid] + adj);
                m3 = fmaxf(m3, Sh[r * 257 + 128 + tid] + adj);
            }
            if (m2 > NEG_INF) {
                float s2 = 0.f;
#pragma unroll 8
                for (int r = 0; r < 32; r++)
                    s2 += __expf(Sh[r * 257 + tid] + rvadj[r] - m2);
                float M = fmaxf(cm0, m2);
                cs0 = cs0 * __expf(cm0 - M) + s2 * __expf(m2 - M);
                cm0 = M;
            }
            if (m3 > NEG_INF) {
                float s3 = 0.f;
#pragma unroll 8
                for (int r = 0; r < 32; r++)
                    s3 += __expf(Sh[r * 257 + 128 + tid] + rvadj[r] - m3);
                float M = fmaxf(cm1, m3);
                cs1 = cs1 * __expf(cm1 - M) + s3 * __expf(m3 - M);
                cm1 = M;
            }
        }
        // denom partials: 128 threads = (row = tid&31, grp = tid>>5 covering 64 cols)
        {
            int row = tid & 31, grp = tid >> 5;
            int l = l0 + h * 32 + row;
            unsigned long long bits = mbits[l * 4 + grp];
            const float* Srow = Sh + row * 257 + grp * 64;
            float m = NEG_INF;
#pragma unroll 8
            for (int c = 0; c < 64; c++) {
                float adj = ((bits >> c) & 1ULL) ? 0.f : NEG_INF;
                m = fmaxf(m, Srow[c] + adj);
            }
            float s = 0.f;
            if (m > NEG_INF) {
#pragma unroll 8
                for (int c = 0; c < 64; c++) {
                    float adj = ((bits >> c) & 1ULL) ? 0.f : NEG_INF;
                    s += __expf(Srow[c] + adj - m);
                }
            }
            pm[grp * 32 + row] = m;
            ps[grp * 32 + row] = s;
        }
        __syncthreads();
        if (tid < 32) {
            float m0v = pm[tid], m1v = pm[32 + tid], m2v = pm[64 + tid], m3v = pm[96 + tid];
            float M = fmaxf(fmaxf(m0v, m1v), fmaxf(m2v, m3v));
            float dl;
            if (M == NEG_INF) dl = NEG_INF;
            else {
                float s = ps[tid] * __expf(m0v - M) + ps[32 + tid] * __expf(m1v - M) +
                          ps[64 + tid] * __expf(m2v - M) + ps[96 + tid] * __expf(m3v - M);
                dl = M + __logf(s);
            }
            int gr = row0 + h * 32 + tid;
            denom[gr] = dl;
            siji[gr] = Sh[tid * 257 + bIdx];
        }
    }
    if (tid == bIdx)       { cm0 = NEG_INF; cs0 = 0.f; }   // k == i exclusion
    if (tid + 128 == bIdx) { cm1 = NEG_INF; cs1 = 0.f; }
    crossM[(size_t)tid * NT + tile] = cm0;
    crossS[(size_t)tid * NT + tile] = cs0;
    crossM[(size_t)(tid + 128) * NT + tile] = cm1;
    crossS[(size_t)(tid + 128) * NT + tile] = cs1;
}

// ---------------- K3: cross_log[i] = merge of 2048 (m,s) partials ----------------
__global__ __launch_bounds__(256) void cross_combine_kernel(const float* __restrict__ crossM,
                                                            const float* __restrict__ crossS,
                                                            float* __restrict__ crossLog) {
    int i = blockIdx.x;
    int tid = threadIdx.x;
    float m = NEG_INF, s = 0.f;
    for (int e = 0; e < NT / 256; e++) {
        int t = e * 256 + tid;
        float m2 = crossM[(size_t)i * NT + t];
        float s2 = crossS[(size_t)i * NT + t];
        if (m2 > NEG_INF) {
            if (m == NEG_INF) { m = m2; s = s2; }
            else {
                float M = fmaxf(m, m2);
                s = s * expf(m - M) + s2 * expf(m2 - M);
                m = M;
            }
        }
    }
    __shared__ float sm[256], ss[256];
    sm[tid] = m; ss[tid] = s;
    __syncthreads();
    for (int off = 128; off > 0; off >>= 1) {
        if (tid < off) {
            float m1 = sm[tid], s1 = ss[tid];
            float m2 = sm[tid + off], s2 = ss[tid + off];
            float M = fmaxf(m1, m2);
            float sv;
            if (M == NEG_INF) sv = 0.f;
            else sv = s1 * expf(m1 - M) + s2 * expf(m2 - M);
            sm[tid] = M; ss[tid] = sv;
        }
        __syncthreads();
    }
    if (tid == 0) crossLog[i] = (sm[0] == NEG_INF) ? NEG_INF : sm[0] + logf(ss[0]);
}

// ---------------- K4: per-block partial loss sums ----------------
__global__ __launch_bounds__(256) void loss_partial_kernel(
    const int* __restrict__ pad, const float* __restrict__ denom,
    const float* __restrict__ siji, const float* __restrict__ crossLog,
    float* __restrict__ psum, float* __restrict__ pcnt) {
    int tid = threadIdx.x;
    int idx = blockIdx.x * 256 + tid;
    float term = 0.f, cnt = 0.f;
    if (pad[idx] == 0) {
        float dl = denom[idx], sv = siji[idx], cl = crossLog[idx >> 9];
        float M = fmaxf(sv, cl);
        float neg = M + log1pf(expf(-fabsf(sv - cl)));
        term = 0.5f * (dl + neg) - sv;
        cnt = 1.f;
    }
    __shared__ float bs[256], bc[256];
    bs[tid] = term; bc[tid] = cnt;
    __syncthreads();
    for (int off = 128; off > 0; off >>= 1) {
        if (tid < off) { bs[tid] += bs[tid + off]; bc[tid] += bc[tid + off]; }
        __syncthreads();
    }
    if (tid == 0) { psum[blockIdx.x] = bs[0]; pcnt[blockIdx.x] = bc[0]; }
}

// ---------------- K5: final reduce of 512 partials ----------------
__global__ __launch_bounds__(256) void final_kernel(const float* __restrict__ psum,
                                                    const float* __restrict__ pcnt,
                                                    float* __restrict__ out) {
    int tid = threadIdx.x;
    __shared__ float bs[256], bc[256];
    bs[tid] = psum[tid] + psum[tid + 256];
    bc[tid] = pcnt[tid] + pcnt[tid + 256];
    __syncthreads();
    for (int off = 128; off > 0; off >>= 1) {
        if (tid < off) { bs[tid] += bs[tid + off]; bc[tid] += bc[tid + off]; }
        __syncthreads();
    }
    if (tid == 0) out[0] = bs[0] / bc[0];
}

extern "C" void kernel_launch(void* const* d_in, const int* in_sizes, int n_in,
                              void* d_out, int out_size, void* d_ws, size_t ws_size,
                              hipStream_t stream) {
    (void)in_sizes; (void)n_in; (void)out_size; (void)ws_size;
    const float* text = (const float*)d_in[0];
    const float* img  = (const float*)d_in[1];
    const float* Wml  = (const float*)d_in[2];
    const float* Wmv  = (const float*)d_in[3];
    const float* tau  = (const float*)d_in[4];
    const int* pad    = (const int*)d_in[5];
    float* out = (float*)d_out;

    float* ws = (float*)d_ws;
    float* ip       = ws;                      // 131072 fl
    unsigned short* Cb2 = (unsigned short*)(ws + 131072);  // 131072 ushort (chunk-major)
    unsigned long long* mbits = (unsigned long long*)(ws + 262144); // 2048 u64
    float* denom    = ws + 266240;             // 131072
    float* siji     = ws + 397312;             // 131072
    float* crossM   = ws + 528384;             // 524288
    float* crossS   = ws + 1052672;            // 524288
    float* crossLog = ws + 1576960;            // 256
    float* psum     = ws + 1577216;            // 512
    float* pcnt     = ws + 1577728;            // 512

    hipLaunchKernelGGL(ip_kernel,   dim3(64),  dim3(256), 0, stream, img, Wmv, ip);
    hipLaunchKernelGGL(c_kernel,    dim3(64),  dim3(256), 0, stream, ip, Wml, tau, Cb2);
    hipLaunchKernelGGL(mask_kernel, dim3(L_),  dim3(256), 0, stream, pad, mbits);
    hipLaunchKernelGGL(gemm_mfma_kernel, dim3(NT), dim3(128), 0, stream,
                       text, Cb2, mbits, denom, siji, crossM, crossS);
    hipLaunchKernelGGL(cross_combine_kernel, dim3(B_), dim3(256), 0, stream,
                       crossM, crossS, crossLog);
    hipLaunchKernelGGL(loss_partial_kernel, dim3(ROWS / 256), dim3(256), 0, stream,
                       pad, denom, siji, crossLog, psum, pcnt);
    hipLaunchKernelGGL(final_kernel, dim3(1), dim3(256), 0, stream, psum, pcnt, out);
}

// Round 2
// 462.231 us; speedup vs baseline: 1.1785x; 1.1785x over previous
//
#include <hip/hip_runtime.h>
#include <math.h>

// LCGLoss: B=256, L=512, D=512.
// S[(b,l),k] = (text @ C^T)[(b,l),k],  C[k][d] = bf16( (ip @ W_ML)[k][d] / tau )
// loss = mean over valid (i,l) of 0.5*(denom_log + logaddexp(s_iji, cross_log[i])) - s_iji
//
// GEMM: 64 rows x 256 cols per block (4 waves, each 32 rows x 128 cols).
// B staged to LDS via global_load_lds DMA (chunk-major Cb2 -> linear dest),
// double-buffered, ONE barrier per K-chunk. A streams HBM->reg->cvt (wave-private).
// Epilogue fully in registers via shfl_xor butterflies (no LDS S-matrix).

#define B_ 256
#define L_ 512
#define D_ 512
#define ROWS (B_ * L_)      // 131072
#define NT (ROWS / 64)      // 2048 row-tiles
#define NEG_INF (-INFINITY)

typedef __attribute__((ext_vector_type(8))) short s8_t;     // 8 bf16 in 4 VGPRs
typedef __attribute__((ext_vector_type(4))) float f4_t;
typedef __attribute__((ext_vector_type(2))) float f2_t;
typedef __attribute__((ext_vector_type(4))) unsigned short us4_t;

typedef __attribute__((address_space(3))) unsigned int lds_u32;
typedef const __attribute__((address_space(1))) unsigned int glb_u32;

__device__ inline unsigned short f2bf(float x) {
    unsigned int u = __float_as_uint(x);
    u += 0x7FFFu + ((u >> 16) & 1u);          // round-to-nearest-even
    return (unsigned short)(u >> 16);
}

// ---------------- K0: ip[k][e] = sum_d img[k][d]*Wmv[e][d]; 32k x 64e tiles, 64 blocks ----
__global__ __launch_bounds__(256) void ip_kernel(const float* __restrict__ img,
                                                 const float* __restrict__ Wmv,
                                                 float* __restrict__ ip) {
    int kt = blockIdx.x >> 3, et = blockIdx.x & 7;
    __shared__ float Ast[32][36];   // [d][krow]  (transposed)
    __shared__ float Bst[32][72];   // [d][ecol]  (transposed, 16B-aligned rows)
    int tid = threadIdx.x;
    int ty = tid >> 4;              // 0..15 -> rows ty*2
    int tx = tid & 15;              // cols tx*4
    float acc[2][4] = {};
    int sr = tid >> 3, sc = (tid & 7) * 4;
    for (int d0 = 0; d0 < D_; d0 += 32) {
        f4_t a = *(const f4_t*)(img + (size_t)(kt * 32 + sr) * D_ + d0 + sc);
        f4_t b0 = *(const f4_t*)(Wmv + (size_t)(et * 64 + sr) * D_ + d0 + sc);
        f4_t b1 = *(const f4_t*)(Wmv + (size_t)(et * 64 + sr + 32) * D_ + d0 + sc);
        __syncthreads();
#pragma unroll
        for (int m = 0; m < 4; m++) {
            Ast[sc + m][sr] = a[m];
            Bst[sc + m][sr] = b0[m];
            Bst[sc + m][sr + 32] = b1[m];
        }
        __syncthreads();
#pragma unroll 4
        for (int d = 0; d < 32; d++) {
            f2_t a2 = *(const f2_t*)&Ast[d][ty * 2];
            f4_t b4 = *(const f4_t*)&Bst[d][tx * 4];
#pragma unroll
            for (int i = 0; i < 2; i++)
#pragma unroll
                for (int j = 0; j < 4; j++) acc[i][j] = fmaf(a2[i], b4[j], acc[i][j]);
        }
    }
#pragma unroll
    for (int i = 0; i < 2; i++) {
        f4_t o; o[0] = acc[i][0]; o[1] = acc[i][1]; o[2] = acc[i][2]; o[3] = acc[i][3];
        *(f4_t*)(ip + (size_t)(kt * 32 + ty * 2 + i) * D_ + et * 64 + tx * 4) = o;
    }
}

// ---------------- K1: Cb2 chunk-major: element (n, kk) at (kk>>3)*2048 + n*8 + (kk&7) ----
__global__ __launch_bounds__(256) void c_kernel(const float* __restrict__ ip,
                                                const float* __restrict__ Wml,
                                                const float* __restrict__ tau,
                                                unsigned short* __restrict__ Cb2) {
    int kt = blockIdx.x >> 3, dt = blockIdx.x & 7;
    __shared__ float Ast[32][36];   // [e][krow] (transposed)
    __shared__ float Bst[32][72];   // [e][dcol] (direct rows of Wml)
    int tid = threadIdx.x;
    int ty = tid >> 4;
    int tx = tid & 15;
    float acc[2][4] = {};
    int sr = tid >> 3, sc = (tid & 7) * 4;       // A staging
    int br = tid >> 4, bc = (tid & 15) * 4;      // B staging (16 rows x 64 cols per pass)
    for (int e0 = 0; e0 < D_; e0 += 32) {
        f4_t a = *(const f4_t*)(ip + (size_t)(kt * 32 + sr) * D_ + e0 + sc);
        f4_t b0 = *(const f4_t*)(Wml + (size_t)(e0 + br) * D_ + dt * 64 + bc);
        f4_t b1 = *(const f4_t*)(Wml + (size_t)(e0 + br + 16) * D_ + dt * 64 + bc);
        __syncthreads();
#pragma unroll
        for (int m = 0; m < 4; m++) Ast[sc + m][sr] = a[m];
        *(f4_t*)&Bst[br][bc] = b0;
        *(f4_t*)&Bst[br + 16][bc] = b1;
        __syncthreads();
#pragma unroll 4
        for (int e = 0; e < 32; e++) {
            f2_t a2 = *(const f2_t*)&Ast[e][ty * 2];
            f4_t b4 = *(const f4_t*)&Bst[e][tx * 4];
#pragma unroll
            for (int i = 0; i < 2; i++)
#pragma unroll
                for (int j = 0; j < 4; j++) acc[i][j] = fmaf(a2[i], b4[j], acc[i][j]);
        }
    }
    float it = 1.0f / fmaxf(tau[0], 0.001f);
#pragma unroll
    for (int i = 0; i < 2; i++) {
        us4_t o;
#pragma unroll
        for (int j = 0; j < 4; j++) o[j] = f2bf(acc[i][j] * it);
        int n = kt * 32 + ty * 2 + i;           // output col (image index)
        int kk0 = dt * 64 + tx * 4;             // GEMM-K coordinate of o[0]
        *(us4_t*)(Cb2 + (size_t)((kk0 >> 3) * 256 + n) * 8 + (kk0 & 7)) = o;
    }
}

// ---------------- Kmask: mbits[l*4+w] bit j = valid[w*64+j, l] ----------------
__global__ __launch_bounds__(256) void mask_kernel(const int* __restrict__ pad,
                                                   unsigned long long* __restrict__ mbits) {
    int l = blockIdx.x;
    int w = threadIdx.x >> 6;
    int j = threadIdx.x & 63;
    unsigned long long bal = __ballot(pad[(w * 64 + j) * L_ + l] == 0);
    if (j == 0) mbits[l * 4 + w] = bal;
}

// value of acc at (mt, nt, r) -- mt/nt/r must be compile-time constants
#define ACC(mt, nt, r) ((mt) ? acc1[nt][r] : acc0[nt][r])

// merge (m,s) with shfl_xor partner
#define MERGE_XOR(m, s, msk) do {                                        \
        float mo_ = __shfl_xor(m, msk);                                  \
        float so_ = __shfl_xor(s, msk);                                  \
        float M_ = fmaxf(m, mo_);                                        \
        s = (M_ > NEG_INF) ? (s * __expf(m - M_) + so_ * __expf(mo_ - M_)) : 0.f; \
        m = M_;                                                          \
    } while (0)

// ---------------- K2: MFMA GEMM, DMA-staged B, 1 barrier/chunk, in-reg epilogue ----------
__global__ __launch_bounds__(256, 3) void gemm_mfma_kernel(
    const float* __restrict__ text, const unsigned short* __restrict__ Cb2,
    const unsigned long long* __restrict__ mbits,
    float* __restrict__ denom, float* __restrict__ siji,
    float* __restrict__ crossM, float* __restrict__ crossS) {
    // B double-buffer: 2 x 16 KB. Epilogue overlays small (m,s) merge tables.
    __shared__ __align__(16) unsigned char smem[32768];

    const int tile = blockIdx.x;
    const int row0 = tile * 64;
    const int bIdx = row0 >> 9;      // batch index (all 64 rows same b)
    const int l0 = row0 & 511;
    const int tid = threadIdx.x;
    const int wave = tid >> 6;
    const int lane = tid & 63;
    const int qd = lane >> 4;        // k-quad / C row-quad
    const int mm = lane & 15;        // A row within 16 / C col within 16
    const int wr = wave >> 1;        // row group (2 x 32 rows)
    const int wc = wave & 1;         // col group (2 x 128 cols)

    f4_t acc0[8], acc1[8];
#pragma unroll
    for (int nt = 0; nt < 8; nt++)
#pragma unroll
        for (int r = 0; r < 4; r++) { acc0[nt][r] = 0.f; acc1[nt][r] = 0.f; }

    // A: wave-private rows. mt=0 rows: row0 + wr*32 + mm; mt=1: +16. k = qd*8 + j.
    const float* aRow = text + (size_t)(row0 + wr * 32 + mm) * D_ + qd * 8;

    f4_t ar[4];
#define LOAD_A(t) do { \
        ar[0] = *(const f4_t*)(aRow + (t) * 32); \
        ar[1] = *(const f4_t*)(aRow + (t) * 32 + 4); \
        ar[2] = *(const f4_t*)(aRow + 16 * D_ + (t) * 32); \
        ar[3] = *(const f4_t*)(aRow + 16 * D_ + (t) * 32 + 4); \
    } while (0)

    // Stage chunk t (16 KB, contiguous in Cb2) into buffer buf via DMA.
    // Each wave issues 4 x 1KB; LDS dest is wave-uniform, lanes fill +lane*16.
#define STAGE(buf, t) do { \
        const unsigned char* gsrc_ = (const unsigned char*)Cb2 + (size_t)(t) * 16384 + wave * 1024 + lane * 16; \
        unsigned char* ldst_ = smem + (buf) * 16384 + wave * 1024; \
        _Pragma("unroll") \
        for (int i_ = 0; i_ < 4; i_++) \
            __builtin_amdgcn_global_load_lds((glb_u32*)(gsrc_ + i_ * 4096), \
                                             (lds_u32*)(ldst_ + i_ * 4096), 16, 0, 0); \
    } while (0)

    STAGE(0, 0);
    LOAD_A(0);
    int cur = 0;
#pragma unroll 1
    for (int t = 0; t < 16; t++) {
        __syncthreads();                          // drains stage(t) (+ A(t)); issued 1 chunk ago
        if (t < 15) STAGE(cur ^ 1, t + 1);        // async into the other buffer
        s8_t aa0, aa1;
#pragma unroll
        for (int j = 0; j < 4; j++) {
            aa0[j] = (short)f2bf(ar[0][j]); aa0[j + 4] = (short)f2bf(ar[1][j]);
            aa1[j] = (short)f2bf(ar[2][j]); aa1[j + 4] = (short)f2bf(ar[3][j]);
        }
        if (t < 15) LOAD_A(t + 1);                // ar free after cvt; covered until next barrier
        const unsigned short* bbase =
            (const unsigned short*)(smem + cur * 16384) + qd * 2048 + (wc * 128 + mm) * 8;
#pragma unroll
        for (int nt = 0; nt < 8; nt++) {
            s8_t bf = *(const s8_t*)(bbase + nt * 128);
            acc0[nt] = __builtin_amdgcn_mfma_f32_16x16x32_bf16(aa0, bf, acc0[nt], 0, 0, 0);
            acc1[nt] = __builtin_amdgcn_mfma_f32_16x16x32_bf16(aa1, bf, acc1[nt], 0, 0, 0);
        }
        cur ^= 1;
    }
    __syncthreads();     // all ds_reads done before LDS overlay reuse

    // -------- epilogue, fully in registers ------------------------------------------------
    // acc(mt,nt,r): row = row0 + wr*32 + mt*16 + qd*4 + r ; col = wc*128 + nt*16 + mm.
    float* fp  = (float*)smem;
    float* pmp = fp;          // [2 wc][64 rows]
    float* psp = fp + 128;
    float* cmp = fp + 256;    // [2 wr][256 cols]
    float* csp = fp + 768;

    const int mw = bIdx >> 6, mb = bIdx & 63;

    // row validity adj (valid[bIdx, l] per row)
    float radj[2][4];
#pragma unroll
    for (int mt = 0; mt < 2; mt++)
#pragma unroll
        for (int r = 0; r < 4; r++) {
            int l = l0 + wr * 32 + mt * 16 + qd * 4 + r;
            radj[mt][r] = ((mbits[l * 4 + mw] >> mb) & 1ULL) ? 0.f : NEG_INF;
        }

    // cross partials per column nt (reduce over this wave's 32 rows, row-masked)
#pragma unroll
    for (int nt = 0; nt < 8; nt++) {
        float m = NEG_INF;
#pragma unroll
        for (int mt = 0; mt < 2; mt++)
#pragma unroll
            for (int r = 0; r < 4; r++) m = fmaxf(m, ACC(mt, nt, r) + radj[mt][r]);
        float s = 0.f;
        if (m > NEG_INF) {
#pragma unroll
            for (int mt = 0; mt < 2; mt++)
#pragma unroll
                for (int r = 0; r < 4; r++) s += __expf(ACC(mt, nt, r) + radj[mt][r] - m);
        }
        MERGE_XOR(m, s, 16);
        MERGE_XOR(m, s, 32);
        if (qd == 0) {
            int col = wc * 128 + nt * 16 + mm;
            cmp[wr * 256 + col] = m;
            csp[wr * 256 + col] = s;
        }
    }

    // denom partials per row (reduce over this wave's 128 cols, col/l-masked)
#pragma unroll
    for (int mt = 0; mt < 2; mt++)
#pragma unroll
        for (int r = 0; r < 4; r++) {
            int rl = wr * 32 + mt * 16 + qd * 4 + r;
            int l = l0 + rl;
            unsigned long long w0 = mbits[l * 4 + wc * 2] >> mm;       // bits nt*16 for nt<4
            unsigned long long w1 = mbits[l * 4 + wc * 2 + 1] >> mm;   // bits (nt-4)*16
            float v[8];
#pragma unroll
            for (int nt = 0; nt < 4; nt++) {
                v[nt]     = ACC(mt, nt, r)     + (((w0 >> (nt * 16)) & 1ULL) ? 0.f : NEG_INF);
                v[nt + 4] = ((mt) ? acc1[nt + 4][r] : acc0[nt + 4][r])
                            + (((w1 >> (nt * 16)) & 1ULL) ? 0.f : NEG_INF);
            }
            float m = NEG_INF;
#pragma unroll
            for (int nt = 0; nt < 8; nt++) m = fmaxf(m, v[nt]);
            float s = 0.f;
            if (m > NEG_INF) {
#pragma unroll
                for (int nt = 0; nt < 8; nt++) s += __expf(v[nt] - m);
            }
            MERGE_XOR(m, s, 1);
            MERGE_XOR(m, s, 2);
            MERGE_XOR(m, s, 4);
            MERGE_XOR(m, s, 8);
            if (mm == 0) { pmp[wc * 64 + rl] = m; psp[wc * 64 + rl] = s; }
        }

    // s_iji: lane holding col == bIdx writes its 8 rows
#pragma unroll
    for (int nt = 0; nt < 8; nt++)
        if (wc == (bIdx >> 7) && mm == (bIdx & 15) && nt == ((bIdx >> 4) & 7)) {
#pragma unroll
            for (int mt = 0; mt < 2; mt++)
#pragma unroll
                for (int r = 0; r < 4; r++)
                    siji[row0 + wr * 32 + mt * 16 + qd * 4 + r] = ACC(mt, nt, r);
        }

    __syncthreads();

    if (tid < 64) {     // denom: merge wc halves
        float m0 = pmp[tid], m1 = pmp[64 + tid];
        float s0 = psp[tid], s1 = psp[64 + tid];
        float M = fmaxf(m0, m1);
        float dl = NEG_INF;
        if (M > NEG_INF) dl = M + __logf(s0 * __expf(m0 - M) + s1 * __expf(m1 - M));
        denom[row0 + tid] = dl;
    }
    {                   // cross: merge wr halves, k==i exclusion, write (m,s) per col
        int col = tid;
        float m0 = cmp[col], m1 = cmp[256 + col];
        float s0 = csp[col], s1 = csp[256 + col];
        float M = fmaxf(m0, m1);
        float s = (M > NEG_INF) ? (s0 * __expf(m0 - M) + s1 * __expf(m1 - M)) : 0.f;
        if (col == bIdx) { M = NEG_INF; s = 0.f; }
        crossM[(size_t)col * NT + tile] = M;
        crossS[(size_t)col * NT + tile] = s;
    }
#undef LOAD_A
#undef STAGE
}

// ---------------- K3: cross_log[i] = merge of 2048 (m,s) partials ----------------
__global__ __launch_bounds__(256) void cross_combine_kernel(const float* __restrict__ crossM,
                                                            const float* __restrict__ crossS,
                                                            float* __restrict__ crossLog) {
    int i = blockIdx.x;
    int tid = threadIdx.x;
    float m = NEG_INF, s = 0.f;
    for (int e = 0; e < NT / 256; e++) {
        int t = e * 256 + tid;
        float m2 = crossM[(size_t)i * NT + t];
        float s2 = crossS[(size_t)i * NT + t];
        if (m2 > NEG_INF) {
            if (m == NEG_INF) { m = m2; s = s2; }
            else {
                float M = fmaxf(m, m2);
                s = s * expf(m - M) + s2 * expf(m2 - M);
                m = M;
            }
        }
    }
    __shared__ float sm[256], ss[256];
    sm[tid] = m; ss[tid] = s;
    __syncthreads();
    for (int off = 128; off > 0; off >>= 1) {
        if (tid < off) {
            float m1 = sm[tid], s1 = ss[tid];
            float m2 = sm[tid + off], s2 = ss[tid + off];
            float M = fmaxf(m1, m2);
            float sv;
            if (M == NEG_INF) sv = 0.f;
            else sv = s1 * expf(m1 - M) + s2 * expf(m2 - M);
            sm[tid] = M; ss[tid] = sv;
        }
        __syncthreads();
    }
    if (tid == 0) crossLog[i] = (sm[0] == NEG_INF) ? NEG_INF : sm[0] + logf(ss[0]);
}

// ---------------- K4: per-block partial loss sums ----------------
__global__ __launch_bounds__(256) void loss_partial_kernel(
    const int* __restrict__ pad, const float* __restrict__ denom,
    const float* __restrict__ siji, const float* __restrict__ crossLog,
    float* __restrict__ psum, float* __restrict__ pcnt) {
    int tid = threadIdx.x;
    int idx = blockIdx.x * 256 + tid;
    float term = 0.f, cnt = 0.f;
    if (pad[idx] == 0) {
        float dl = denom[idx], sv = siji[idx], cl = crossLog[idx >> 9];
        float M = fmaxf(sv, cl);
        float neg = M + log1pf(expf(-fabsf(sv - cl)));
        term = 0.5f * (dl + neg) - sv;
        cnt = 1.f;
    }
    __shared__ float bs[256], bc[256];
    bs[tid] = term; bc[tid] = cnt;
    __syncthreads();
    for (int off = 128; off > 0; off >>= 1) {
        if (tid < off) { bs[tid] += bs[tid + off]; bc[tid] += bc[tid + off]; }
        __syncthreads();
    }
    if (tid == 0) { psum[blockIdx.x] = bs[0]; pcnt[blockIdx.x] = bc[0]; }
}

// ---------------- K5: final reduce of 512 partials ----------------
__global__ __launch_bounds__(256) void final_kernel(const float* __restrict__ psum,
                                                    const float* __restrict__ pcnt,
                                                    float* __restrict__ out) {
    int tid = threadIdx.x;
    __shared__ float bs[256], bc[256];
    bs[tid] = psum[tid] + psum[tid + 256];
    bc[tid] = pcnt[tid] + pcnt[tid + 256];
    __syncthreads();
    for (int off = 128; off > 0; off >>= 1) {
        if (tid < off) { bs[tid] += bs[tid + off]; bc[tid] += bc[tid + off]; }
        __syncthreads();
    }
    if (tid == 0) out[0] = bs[0] / bc[0];
}

extern "C" void kernel_launch(void* const* d_in, const int* in_sizes, int n_in,
                              void* d_out, int out_size, void* d_ws, size_t ws_size,
                              hipStream_t stream) {
    (void)in_sizes; (void)n_in; (void)out_size; (void)ws_size;
    const float* text = (const float*)d_in[0];
    const float* img  = (const float*)d_in[1];
    const float* Wml  = (const float*)d_in[2];
    const float* Wmv  = (const float*)d_in[3];
    const float* tau  = (const float*)d_in[4];
    const int* pad    = (const int*)d_in[5];
    float* out = (float*)d_out;

    float* ws = (float*)d_ws;
    float* ip       = ws;                      // 131072 fl
    unsigned short* Cb2 = (unsigned short*)(ws + 131072);  // 131072 ushort (chunk-major)
    unsigned long long* mbits = (unsigned long long*)(ws + 262144); // 2048 u64
    float* denom    = ws + 266240;             // 131072
    float* siji     = ws + 397312;             // 131072
    float* crossM   = ws + 528384;             // 524288
    float* crossS   = ws + 1052672;            // 524288
    float* crossLog = ws + 1576960;            // 256
    float* psum     = ws + 1577216;            // 512
    float* pcnt     = ws + 1577728;            // 512

    hipLaunchKernelGGL(ip_kernel,   dim3(64),  dim3(256), 0, stream, img, Wmv, ip);
    hipLaunchKernelGGL(c_kernel,    dim3(64),  dim3(256), 0, stream, ip, Wml, tau, Cb2);
    hipLaunchKernelGGL(mask_kernel, dim3(L_),  dim3(256), 0, stream, pad, mbits);
    hipLaunchKernelGGL(gemm_mfma_kernel, dim3(NT), dim3(256), 0, stream,
                       text, Cb2, mbits, denom, siji, crossM, crossS);
    hipLaunchKernelGGL(cross_combine_kernel, dim3(B_), dim3(256), 0, stream,
                       crossM, crossS, crossLog);
    hipLaunchKernelGGL(loss_partial_kernel, dim3(ROWS / 256), dim3(256), 0, stream,
                       pad, denom, siji, crossLog, psum, pcnt);
    hipLaunchKernelGGL(final_kernel, dim3(1), dim3(256), 0, stream, psum, pcnt, out);
}